// Round 2
// baseline (388.513 us; speedup 1.0000x reference)
//
#include <hip/hip_runtime.h>

#define MDIM 8192
#define NDIM 4096
#define KDIM 4096
#define BM 256
#define BN 256
#define BK 128

typedef int v4i __attribute__((ext_vector_type(4)));
typedef int v16i __attribute__((ext_vector_type(16)));

__device__ __forceinline__ unsigned pack4(int x, int y, int z, int w) {
    return (unsigned)(x & 0xff) | ((unsigned)(y & 0xff) << 8) |
           ((unsigned)(z & 0xff) << 16) | ((unsigned)w << 24);
}

// ---- pass 1: int32 -> packed int8, pre-tiled ----
// Both A and B tiles are 256 rows x 128 k, granule-major [kb 0..7][row 0..255],
// granule = 16 bytes of k for one row. This is the exact MFMA fragment order:
// frag(row, ks) reads granule (kb = 2*ks + (lane>>5), row) -> contiguous,
// conflict-free ds_read_b128, and DMA-linear staging (layout preserved).
// A: 32 mtiles x 32 kiters = 1024 blocks; B: 16 ntiles x 32 kiters = 512.
__global__ __launch_bounds__(256) void pack_tiled(const int* __restrict__ x,
                                                  const int* __restrict__ w,
                                                  uint4* __restrict__ xp,
                                                  uint4* __restrict__ wp) {
    __shared__ unsigned lds32[256 * 33];
    const int wg  = blockIdx.x;
    const int tid = threadIdx.x;
    const int kq   = tid & 31;
    const int rsub = tid >> 5;

    const int* src;
    uint4* dst;
    if (wg < 1024) {
        const int mtile = wg >> 5, kiter = wg & 31;
        src = x + (size_t)(mtile * 256) * KDIM + kiter * 128;
        dst = xp + (size_t)(mtile * 32 + kiter) * 2048;
    } else {
        const int ntile = (wg - 1024) >> 5, kiter = wg & 31;
        src = w + (size_t)(ntile * 256) * KDIM + kiter * 128;
        dst = wp + (size_t)(ntile * 32 + kiter) * 2048;
    }
#pragma unroll
    for (int it = 0; it < 32; ++it) {
        const int row = it * 8 + rsub;
        int4 v = *(const int4*)(src + (size_t)row * KDIM + kq * 4);
        lds32[row * 33 + kq] = pack4(v.x, v.y, v.z, v.w);
    }
    __syncthreads();
#pragma unroll
    for (int it = 0; it < 8; ++it) {
        const int g = it * 256 + tid;
        const int kb = g >> 8, row = g & 255;
        const unsigned* p = &lds32[row * 33 + kb * 4];
        uint4 o;
        o.x = p[0]; o.y = p[1]; o.z = p[2]; o.w = p[3];
        dst[g] = o;
    }
}

// ---- pass 2: int8 GEMM, out = x @ W^T ----
// 8-phase 256x256 template (m194-m201) ported to i8:
//   512 threads, 8 waves (2M x 4N), wave tile 128x64, acc[4][2] v16i.
//   LDS 128 KB: buf b at b*65536: A tile 32 KB, B tile 32 KB (both DMA'd).
//   4 phases per K-tile; phase = C-quadrant (2mt x 1nt) x 4ks = 8 MFMA.
//   Per phase: ds_read subtile; issue 4 global_load_lds (phases 0,1 only,
//   staging tile t+1 -> other buf); raw s_barrier; asm lgkmcnt(0)+
//   sched_barrier(0) (rule #18); setprio(1) 8 MFMA setprio(0);
//   [phase 3: vmcnt(0) -- 2-3 phases of coverage, not a zero-coverage
//   drain]; raw s_barrier. No __syncthreads in the hot loop (its implicit
//   vmcnt(0)-per-barrier is the m97-structure stall).
__global__ __launch_bounds__(512, 2) void gemm_i8_8ph(const char* __restrict__ Ap,
                                                      const char* __restrict__ Bp,
                                                      const _Float16* __restrict__ bias,
                                                      _Float16* __restrict__ out) {
    __shared__ __align__(16) char lds[131072];

    const int tid  = threadIdx.x;
    const int lane = tid & 63;
    const int wave = tid >> 6;
    const int wr   = wave >> 2;   // 0..1  (M half)
    const int wcn  = wave & 3;    // 0..3  (N quarter)
    const int l31  = lane & 31;
    const int kg   = lane >> 5;

    // bijective XCD-chunked swizzle: 512 blocks, 8 XCDs, region 4bx x 16by.
    const int lid = blockIdx.y * 16 + blockIdx.x;
    const int xc  = lid & 7, ii = lid >> 3;
    const int bx  = (xc & 3) * 4 + (ii & 3);   // 0..15
    const int by  = (xc >> 2) * 16 + (ii >> 2);  // 0..31
    const int bm0 = by * BM;
    const int bn0 = bx * BN;

    const char* apan = Ap + (size_t)by * (BM * KDIM) + tid * 16;
    const char* bpan = Bp + (size_t)bx * (BN * KDIM) + tid * 16;

    int aoff[4], boff[2];
#pragma unroll
    for (int mt = 0; mt < 4; ++mt)
        aoff[mt] = kg * 4096 + (wr * 128 + mt * 32 + l31) * 16;
#pragma unroll
    for (int nt = 0; nt < 2; ++nt)
        boff[nt] = kg * 4096 + (wcn * 64 + nt * 32 + l31) * 16;

    v16i acc[4][2];
#pragma unroll
    for (int mt = 0; mt < 4; ++mt)
#pragma unroll
        for (int nt = 0; nt < 2; ++nt)
#pragma unroll
            for (int i = 0; i < 16; ++i) acc[mt][nt][i] = 0;

    // stage one 32 KB region (4 chunks x 8 KB) of tile t+1; p includes tid*16
    auto stageA = [&](int nb, const char* p) {
#pragma unroll
        for (int c2 = 0; c2 < 4; ++c2)
            __builtin_amdgcn_global_load_lds(
                (__attribute__((address_space(1))) const void*)(p + c2 * 8192),
                (__attribute__((address_space(3))) void*)(lds + nb + c2 * 8192 + tid * 16),
                16, 0, 0);
    };
    auto stageB = [&](int nb, const char* p) {
#pragma unroll
        for (int c2 = 0; c2 < 4; ++c2)
            __builtin_amdgcn_global_load_lds(
                (__attribute__((address_space(1))) const void*)(p + c2 * 8192),
                (__attribute__((address_space(3))) void*)(lds + nb + 32768 + c2 * 8192 + tid * 16),
                16, 0, 0);
    };

    v4i af[8], bf[4];
    auto ldsub = [&](int base, int mp, int nth) {
        if (nth == 0) {
#pragma unroll
            for (int m2 = 0; m2 < 2; ++m2)
#pragma unroll
                for (int ks = 0; ks < 4; ++ks)
                    af[m2 * 4 + ks] =
                        *(const v4i*)(lds + base + ks * 8192 + aoff[mp * 2 + m2]);
        }
#pragma unroll
        for (int ks = 0; ks < 4; ++ks)
            bf[ks] = *(const v4i*)(lds + base + 32768 + ks * 8192 + boff[nth]);
    };
    auto cluster = [&](int mp, int nth) {
        __builtin_amdgcn_s_setprio(1);
#pragma unroll
        for (int ks = 0; ks < 4; ++ks)
#pragma unroll
            for (int m2 = 0; m2 < 2; ++m2)
                acc[mp * 2 + m2][nth] = __builtin_amdgcn_mfma_i32_32x32x32_i8(
                    af[m2 * 4 + ks], bf[ks], acc[mp * 2 + m2][nth], 0, 0, 0);
        __builtin_amdgcn_s_setprio(0);
    };

#define BAR   __builtin_amdgcn_s_barrier()
#define LGKM0 do { asm volatile("s_waitcnt lgkmcnt(0)" ::: "memory"); \
                   __builtin_amdgcn_sched_barrier(0); } while (0)
#define VM0   asm volatile("s_waitcnt vmcnt(0)" ::: "memory")

    auto tile = [&](int base, int nb, bool stg) {
        // phase 0: quadrant (mt 0-1, nt 0) + stage A(t+1)
        ldsub(base, 0, 0);
        if (stg) stageA(nb, apan);
        BAR; LGKM0; cluster(0, 0); BAR;
        // phase 1: quadrant (mt 0-1, nt 1) + stage B(t+1)
        ldsub(base, 0, 1);
        if (stg) stageB(nb, bpan);
        BAR; LGKM0; cluster(0, 1); BAR;
        // phase 2: quadrant (mt 2-3, nt 0)
        ldsub(base, 1, 0);
        BAR; LGKM0; cluster(1, 0); BAR;
        // phase 3: quadrant (mt 2-3, nt 1); tile-end counted drain
        ldsub(base, 1, 1);
        BAR; LGKM0; cluster(1, 1);
        if (stg) VM0;   // A DMAs have ~3 phases, B DMAs ~2 phases of coverage
        BAR;
    };

    // prologue: stage tile 0 -> buf 0 (one-time full drain)
    stageA(0, apan);
    stageB(0, bpan);
    apan += BM * BK;
    bpan += BN * BK;
    VM0; BAR;

#pragma unroll 1
    for (int t2 = 0; t2 < 15; ++t2) {  // tiles 0..29
        tile(0, 65536, true);
        apan += BM * BK; bpan += BN * BK;
        tile(65536, 0, true);
        apan += BM * BK; bpan += BN * BK;
    }
    tile(0, 65536, true);    // tile 30, stages tile 31
    tile(65536, 0, false);   // tile 31

#undef BAR
#undef LGKM0
#undef VM0

    // epilogue: int32 -> fp16 (exact; overflow -> inf matches ref), + bias.
    // C/D layout: col=lane&31, row=(reg&3)+8*(reg>>2)+4*(lane>>5)
    const _Float16 bv0 = bias[bn0 + wcn * 64 + l31];
    const _Float16 bv1 = bias[bn0 + wcn * 64 + 32 + l31];
#pragma unroll
    for (int mt = 0; mt < 4; ++mt) {
#pragma unroll
        for (int nt = 0; nt < 2; ++nt) {
            const int gcol = bn0 + wcn * 64 + nt * 32 + l31;
            const _Float16 bb = nt ? bv1 : bv0;
#pragma unroll
            for (int r = 0; r < 16; ++r) {
                const int rit  = (r & 3) + 8 * (r >> 2) + 4 * kg;
                const int grow = bm0 + wr * 128 + mt * 32 + rit;
                _Float16 h = (_Float16)(float)acc[mt][nt][r] + bb;
                out[(size_t)grow * NDIM + gcol] = h;
            }
        }
    }
}

// ---- fallback (no workspace): non-pipelined, packs in regs ---- (old geometry)
__global__ __launch_bounds__(256, 2) void gemm_i8_fb(const int* __restrict__ A32,
                                                     const int* __restrict__ B32,
                                                     const _Float16* __restrict__ bias,
                                                     _Float16* __restrict__ out) {
    __shared__ char lds[32768];
    const int tid  = threadIdx.x;
    const int lane = tid & 63;
    const int wave = tid >> 6;
    const int bm0 = blockIdx.y * 256;
    const int bn0 = blockIdx.x * 128;
    const int wr  = wave >> 1;
    const int wc  = wave & 1;
    const int l31 = lane & 31;
    const int kg  = lane >> 5;

    int abase[4];
#pragma unroll
    for (int mt = 0; mt < 4; ++mt)
        abase[mt] = kg * 4096 + (wr * 128 + mt * 32 + l31) * 16;

    v16i acc[4][2];
#pragma unroll
    for (int mt = 0; mt < 4; ++mt)
#pragma unroll
        for (int nt = 0; nt < 2; ++nt)
#pragma unroll
            for (int i = 0; i < 16; ++i) acc[mt][nt][i] = 0;

    int aoffs[8];
#pragma unroll
    for (int r = 0; r < 8; ++r) {
        const int c = r * 4 + wave;
        aoffs[r] = (bm0 + (c & 3) * 64 + lane) * KDIM + (c >> 2) * 16;
    }
    for (int k0 = 0; k0 < KDIM; k0 += 128) {
        v4i bfx[2][4];
#pragma unroll
        for (int r = 0; r < 8; ++r) {
            const int c = r * 4 + wave;
            const int4* s = (const int4*)(A32 + (size_t)aoffs[r]);
            int4 v0 = s[0], v1 = s[1], v2 = s[2], v3 = s[3];
            uint4 pk;
            pk.x = pack4(v0.x, v0.y, v0.z, v0.w);
            pk.y = pack4(v1.x, v1.y, v1.z, v1.w);
            pk.z = pack4(v2.x, v2.y, v2.z, v2.w);
            pk.w = pack4(v3.x, v3.y, v3.z, v3.w);
            *(uint4*)(lds + c * 1024 + lane * 16) = pk;
            aoffs[r] += 128;
        }
#pragma unroll
        for (int nt = 0; nt < 2; ++nt)
#pragma unroll
            for (int ks = 0; ks < 4; ++ks) {
                const int* s = B32 + (size_t)(bn0 + wc * 64 + nt * 32 + l31) * KDIM
                               + k0 + (2 * ks + kg) * 16;
                int4 v0 = ((const int4*)s)[0], v1 = ((const int4*)s)[1];
                int4 v2 = ((const int4*)s)[2], v3 = ((const int4*)s)[3];
                bfx[nt][ks][0] = (int)pack4(v0.x, v0.y, v0.z, v0.w);
                bfx[nt][ks][1] = (int)pack4(v1.x, v1.y, v1.z, v1.w);
                bfx[nt][ks][2] = (int)pack4(v2.x, v2.y, v2.z, v2.w);
                bfx[nt][ks][3] = (int)pack4(v3.x, v3.y, v3.z, v3.w);
            }
        __syncthreads();
#pragma unroll
        for (int ks = 0; ks < 4; ++ks) {
            v4i afr[4];
#pragma unroll
            for (int mt = 0; mt < 4; ++mt)
                afr[mt] = *(const v4i*)(lds + abase[mt] + ks * 8192);
#pragma unroll
            for (int mt = 0; mt < 4; ++mt)
#pragma unroll
                for (int nt = 0; nt < 2; ++nt)
                    acc[mt][nt] = __builtin_amdgcn_mfma_i32_32x32x32_i8(
                        afr[mt], bfx[nt][ks], acc[mt][nt], 0, 0, 0);
        }
        __syncthreads();
    }

    const _Float16 bv0 = bias[bn0 + wc * 64 + l31];
    const _Float16 bv1 = bias[bn0 + wc * 64 + 32 + l31];
#pragma unroll
    for (int mt = 0; mt < 4; ++mt) {
#pragma unroll
        for (int nt = 0; nt < 2; ++nt) {
            const int gcol = bn0 + wc * 64 + nt * 32 + l31;
            const _Float16 bb = nt ? bv1 : bv0;
#pragma unroll
            for (int r = 0; r < 16; ++r) {
                const int rit  = (r & 3) + 8 * (r >> 2) + 4 * kg;
                const int grow = bm0 + wr * 128 + mt * 32 + rit;
                _Float16 h = (_Float16)(float)acc[mt][nt][r] + bb;
                out[(size_t)grow * NDIM + gcol] = h;
            }
        }
    }
}

extern "C" void kernel_launch(void* const* d_in, const int* in_sizes, int n_in,
                              void* d_out, int out_size, void* d_ws, size_t ws_size,
                              hipStream_t stream) {
    const int* x = (const int*)d_in[0];
    const int* w = (const int*)d_in[1];
    const _Float16* bias = (const _Float16*)d_in[2];
    _Float16* out = (_Float16*)d_out;

    const size_t xbytes = (size_t)MDIM * KDIM;  // packed int8 bytes
    const size_t wbytes = (size_t)NDIM * KDIM;

    if (ws_size >= xbytes + wbytes) {
        char* xp = (char*)d_ws;
        char* wp = xp + xbytes;
        pack_tiled<<<1536, 256, 0, stream>>>(x, w, (uint4*)xp, (uint4*)wp);
        gemm_i8_8ph<<<dim3(NDIM / BN, MDIM / BM), 512, 0, stream>>>(
            (const char*)xp, (const char*)wp, bias, out);
    } else {
        gemm_i8_fb<<<dim3(NDIM / 128, MDIM / 256), 256, 0, stream>>>(
            x, w, bias, out);
    }
}

// Round 3
// 381.461 us; speedup vs baseline: 1.0185x; 1.0185x over previous
//
#include <hip/hip_runtime.h>

#define MDIM 8192
#define NDIM 4096
#define KDIM 4096
#define BM 256
#define BN 256
#define BK 128

typedef int v4i __attribute__((ext_vector_type(4)));
typedef int v16i __attribute__((ext_vector_type(16)));

__device__ __forceinline__ unsigned pack4(int x, int y, int z, int w) {
    return (unsigned)(x & 0xff) | ((unsigned)(y & 0xff) << 8) |
           ((unsigned)(z & 0xff) << 16) | ((unsigned)w << 24);
}

// ---- pass 1: int32 -> packed int8, pre-tiled ---- (unchanged from R2)
// A and B tiles: 256 rows x 128 k, granule-major [kb 0..7][row 0..255],
// granule = 16 B of k for one row == exact MFMA fragment order.
__global__ __launch_bounds__(256) void pack_tiled(const int* __restrict__ x,
                                                  const int* __restrict__ w,
                                                  uint4* __restrict__ xp,
                                                  uint4* __restrict__ wp) {
    __shared__ unsigned lds32[256 * 33];
    const int wg  = blockIdx.x;
    const int tid = threadIdx.x;
    const int kq   = tid & 31;
    const int rsub = tid >> 5;

    const int* src;
    uint4* dst;
    if (wg < 1024) {
        const int mtile = wg >> 5, kiter = wg & 31;
        src = x + (size_t)(mtile * 256) * KDIM + kiter * 128;
        dst = xp + (size_t)(mtile * 32 + kiter) * 2048;
    } else {
        const int ntile = (wg - 1024) >> 5, kiter = wg & 31;
        src = w + (size_t)(ntile * 256) * KDIM + kiter * 128;
        dst = wp + (size_t)(ntile * 32 + kiter) * 2048;
    }
#pragma unroll
    for (int it = 0; it < 32; ++it) {
        const int row = it * 8 + rsub;
        int4 v = *(const int4*)(src + (size_t)row * KDIM + kq * 4);
        lds32[row * 33 + kq] = pack4(v.x, v.y, v.z, v.w);
    }
    __syncthreads();
#pragma unroll
    for (int it = 0; it < 8; ++it) {
        const int g = it * 256 + tid;
        const int kb = g >> 8, row = g & 255;
        const unsigned* p = &lds32[row * 33 + kb * 4];
        uint4 o;
        o.x = p[0]; o.y = p[1]; o.z = p[2]; o.w = p[3];
        dst[g] = o;
    }
}

// ---- pass 2: int8 GEMM, out = x @ W^T ----
// 256x256 tile, 8 waves (2M x 4N), wave tile 128x64, acc[4][2] v16i.
// LDS 128 KB double buffer, both A and B DMA-staged (global_load_lds w16).
// R3 restructure (LDS-overlap): the R2 lockstep 8-phase serialized LDS
// service (2340 cyc/tile @112 B/cyc) against MFMA (2500 cyc/tile) -> 45%
// cap. Now: ONE barrier per tile; bf[2][4] held in regs for the whole
// tile (8 reads, not 16 -> 192 KB/CU-tile); af ping-pong pipeline: issue
// ks+1's 4 A-frag ds_reads, sched_barrier(0) fence, 8 MFMA on ks. The
// compiler emits counted lgkmcnt(4), so ks+1's LDS service overlaps ks's
// MFMA cluster. vmcnt(0)+barrier at tile top drains stage(t), which was
// issued a full tile (~3000 cyc) earlier -> near-zero stall; stage(t+1)
// issues immediately after the barrier (full-tile coverage, WAR-safe).
__global__ __launch_bounds__(512, 2) void gemm_i8_olp(const char* __restrict__ Ap,
                                                      const char* __restrict__ Bp,
                                                      const _Float16* __restrict__ bias,
                                                      _Float16* __restrict__ out) {
    __shared__ __align__(16) char lds[131072];

    const int tid  = threadIdx.x;
    const int lane = tid & 63;
    const int wave = tid >> 6;
    const int wr   = wave >> 2;   // 0..1  (M half)
    const int wcn  = wave & 3;    // 0..3  (N quarter)
    const int l31  = lane & 31;
    const int kg   = lane >> 5;

    // bijective XCD-chunked swizzle: 512 blocks, 8 XCDs, region 4bx x 16by.
    const int lid = blockIdx.y * 16 + blockIdx.x;
    const int xc  = lid & 7, ii = lid >> 3;
    const int bx  = (xc & 3) * 4 + (ii & 3);     // 0..15
    const int by  = (xc >> 2) * 16 + (ii >> 2);  // 0..31
    const int bm0 = by * BM;
    const int bn0 = bx * BN;

    const char* apan = Ap + (size_t)by * (BM * KDIM) + tid * 16;
    const char* bpan = Bp + (size_t)bx * (BN * KDIM) + tid * 16;

    int aoff[4], boff[2];
#pragma unroll
    for (int mt = 0; mt < 4; ++mt)
        aoff[mt] = (wr * 128 + mt * 32 + l31) * 16 + kg * 4096;
#pragma unroll
    for (int nt = 0; nt < 2; ++nt)
        boff[nt] = (wcn * 64 + nt * 32 + l31) * 16 + kg * 4096;

    v16i acc[4][2];
#pragma unroll
    for (int mt = 0; mt < 4; ++mt)
#pragma unroll
        for (int nt = 0; nt < 2; ++nt)
#pragma unroll
            for (int i = 0; i < 16; ++i) acc[mt][nt][i] = 0;

    // stage 32 KB of A / B of tile t+1 into LDS buffer at byte offset nb
    auto stageA = [&](int nb, const char* p) {
#pragma unroll
        for (int c2 = 0; c2 < 4; ++c2)
            __builtin_amdgcn_global_load_lds(
                (__attribute__((address_space(1))) const void*)(p + c2 * 8192),
                (__attribute__((address_space(3))) void*)(lds + nb + c2 * 8192 + tid * 16),
                16, 0, 0);
    };
    auto stageB = [&](int nb, const char* p) {
#pragma unroll
        for (int c2 = 0; c2 < 4; ++c2)
            __builtin_amdgcn_global_load_lds(
                (__attribute__((address_space(1))) const void*)(p + c2 * 8192),
                (__attribute__((address_space(3))) void*)(lds + nb + 32768 + c2 * 8192 + tid * 16),
                16, 0, 0);
    };

    auto mfma8 = [&](const v4i (&af)[4], const v4i (&bfk)[2]) {
        __builtin_amdgcn_s_setprio(1);
#pragma unroll
        for (int mt = 0; mt < 4; ++mt)
#pragma unroll
            for (int nt = 0; nt < 2; ++nt)
                acc[mt][nt] = __builtin_amdgcn_mfma_i32_32x32x32_i8(
                    af[mt], bfk[nt], acc[mt][nt], 0, 0, 0);
        __builtin_amdgcn_s_setprio(0);
    };

    auto tile = [&](int base, int nb, bool stg) {
        // tile boundary: stage(t) (issued one full tile ago) must be complete
        // in LDS before any wave reads it. Own-wave drain + barrier.
        asm volatile("s_waitcnt vmcnt(0)" ::: "memory");
        __builtin_amdgcn_s_barrier();
        __builtin_amdgcn_sched_barrier(0);  // pin reads below the barrier
        if (stg) {  // prefetch tile t+1 into the other buffer (WAR-safe: all
                    // waves passed the barrier, so t-1 reads are retired)
            stageA(nb, apan);
            stageB(nb, bpan);
            apan += BM * BK;
            bpan += BN * BK;
        }
        // B fragments for the whole tile: 8 reads, held in regs
        v4i bf[2][4];
#pragma unroll
        for (int nt = 0; nt < 2; ++nt)
#pragma unroll
            for (int ks = 0; ks < 4; ++ks)
                bf[nt][ks] = *(const v4i*)(lds + base + 32768 + ks * 8192 + boff[nt]);
        // A fragment ping-pong pipeline over ks
        v4i afA[4], afB[4];
#pragma unroll
        for (int mt = 0; mt < 4; ++mt)
            afA[mt] = *(const v4i*)(lds + base + aoff[mt]);
        __builtin_amdgcn_sched_barrier(0);
        // ks = 0 (issue ks=1 reads first; they service under the MFMAs)
#pragma unroll
        for (int mt = 0; mt < 4; ++mt)
            afB[mt] = *(const v4i*)(lds + base + 8192 + aoff[mt]);
        __builtin_amdgcn_sched_barrier(0);
        {
            v4i bfk[2] = {bf[0][0], bf[1][0]};
            mfma8(afA, bfk);
        }
        // ks = 1
#pragma unroll
        for (int mt = 0; mt < 4; ++mt)
            afA[mt] = *(const v4i*)(lds + base + 16384 + aoff[mt]);
        __builtin_amdgcn_sched_barrier(0);
        {
            v4i bfk[2] = {bf[0][1], bf[1][1]};
            mfma8(afB, bfk);
        }
        // ks = 2
#pragma unroll
        for (int mt = 0; mt < 4; ++mt)
            afB[mt] = *(const v4i*)(lds + base + 24576 + aoff[mt]);
        __builtin_amdgcn_sched_barrier(0);
        {
            v4i bfk[2] = {bf[0][2], bf[1][2]};
            mfma8(afA, bfk);
        }
        // ks = 3
        {
            v4i bfk[2] = {bf[0][3], bf[1][3]};
            mfma8(afB, bfk);
        }
    };

    // prologue: issue stage of tile 0 into buf 0 (drained at first tile top)
    stageA(0, apan);
    stageB(0, bpan);
    apan += BM * BK;
    bpan += BN * BK;

#pragma unroll 1
    for (int t = 0; t < 31; ++t) {
        const int base = (t & 1) ? 65536 : 0;
        tile(base, base ^ 65536, true);
    }
    tile(65536, 0, false);  // tile 31

    // epilogue: int32 -> fp16 (exact; overflow -> inf matches ref), + bias.
    // C/D layout: col=lane&31, row=(reg&3)+8*(reg>>2)+4*(lane>>5)
    const _Float16 bv0 = bias[bn0 + wcn * 64 + l31];
    const _Float16 bv1 = bias[bn0 + wcn * 64 + 32 + l31];
#pragma unroll
    for (int mt = 0; mt < 4; ++mt) {
#pragma unroll
        for (int nt = 0; nt < 2; ++nt) {
            const int gcol = bn0 + wcn * 64 + nt * 32 + l31;
            const _Float16 bb = nt ? bv1 : bv0;
#pragma unroll
            for (int r = 0; r < 16; ++r) {
                const int rit  = (r & 3) + 8 * (r >> 2) + 4 * kg;
                const int grow = bm0 + wr * 128 + mt * 32 + rit;
                _Float16 h = (_Float16)(float)acc[mt][nt][r] + bb;
                out[(size_t)grow * NDIM + gcol] = h;
            }
        }
    }
}

// ---- fallback (no workspace): non-pipelined, packs in regs ---- (unchanged)
__global__ __launch_bounds__(256, 2) void gemm_i8_fb(const int* __restrict__ A32,
                                                     const int* __restrict__ B32,
                                                     const _Float16* __restrict__ bias,
                                                     _Float16* __restrict__ out) {
    __shared__ char lds[32768];
    const int tid  = threadIdx.x;
    const int lane = tid & 63;
    const int wave = tid >> 6;
    const int bm0 = blockIdx.y * 256;
    const int bn0 = blockIdx.x * 128;
    const int wr  = wave >> 1;
    const int wc  = wave & 1;
    const int l31 = lane & 31;
    const int kg  = lane >> 5;

    int abase[4];
#pragma unroll
    for (int mt = 0; mt < 4; ++mt)
        abase[mt] = kg * 4096 + (wr * 128 + mt * 32 + l31) * 16;

    v16i acc[4][2];
#pragma unroll
    for (int mt = 0; mt < 4; ++mt)
#pragma unroll
        for (int nt = 0; nt < 2; ++nt)
#pragma unroll
            for (int i = 0; i < 16; ++i) acc[mt][nt][i] = 0;

    int aoffs[8];
#pragma unroll
    for (int r = 0; r < 8; ++r) {
        const int c = r * 4 + wave;
        aoffs[r] = (bm0 + (c & 3) * 64 + lane) * KDIM + (c >> 2) * 16;
    }
    for (int k0 = 0; k0 < KDIM; k0 += 128) {
        v4i bfx[2][4];
#pragma unroll
        for (int r = 0; r < 8; ++r) {
            const int c = r * 4 + wave;
            const int4* s = (const int4*)(A32 + (size_t)aoffs[r]);
            int4 v0 = s[0], v1 = s[1], v2 = s[2], v3 = s[3];
            uint4 pk;
            pk.x = pack4(v0.x, v0.y, v0.z, v0.w);
            pk.y = pack4(v1.x, v1.y, v1.z, v1.w);
            pk.z = pack4(v2.x, v2.y, v2.z, v2.w);
            pk.w = pack4(v3.x, v3.y, v3.z, v3.w);
            *(uint4*)(lds + c * 1024 + lane * 16) = pk;
            aoffs[r] += 128;
        }
#pragma unroll
        for (int nt = 0; nt < 2; ++nt)
#pragma unroll
            for (int ks = 0; ks < 4; ++ks) {
                const int* s = B32 + (size_t)(bn0 + wc * 64 + nt * 32 + l31) * KDIM
                               + k0 + (2 * ks + kg) * 16;
                int4 v0 = ((const int4*)s)[0], v1 = ((const int4*)s)[1];
                int4 v2 = ((const int4*)s)[2], v3 = ((const int4*)s)[3];
                bfx[nt][ks][0] = (int)pack4(v0.x, v0.y, v0.z, v0.w);
                bfx[nt][ks][1] = (int)pack4(v1.x, v1.y, v1.z, v1.w);
                bfx[nt][ks][2] = (int)pack4(v2.x, v2.y, v2.z, v2.w);
                bfx[nt][ks][3] = (int)pack4(v3.x, v3.y, v3.z, v3.w);
            }
        __syncthreads();
#pragma unroll
        for (int ks = 0; ks < 4; ++ks) {
            v4i afr[4];
#pragma unroll
            for (int mt = 0; mt < 4; ++mt)
                afr[mt] = *(const v4i*)(lds + abase[mt] + ks * 8192);
#pragma unroll
            for (int mt = 0; mt < 4; ++mt)
#pragma unroll
                for (int nt = 0; nt < 2; ++nt)
                    acc[mt][nt] = __builtin_amdgcn_mfma_i32_32x32x32_i8(
                        afr[mt], bfx[nt][ks], acc[mt][nt], 0, 0, 0);
        }
        __syncthreads();
    }

    const _Float16 bv0 = bias[bn0 + wc * 64 + l31];
    const _Float16 bv1 = bias[bn0 + wc * 64 + 32 + l31];
#pragma unroll
    for (int mt = 0; mt < 4; ++mt) {
#pragma unroll
        for (int nt = 0; nt < 2; ++nt) {
            const int gcol = bn0 + wc * 64 + nt * 32 + l31;
            const _Float16 bb = nt ? bv1 : bv0;
#pragma unroll
            for (int r = 0; r < 16; ++r) {
                const int rit  = (r & 3) + 8 * (r >> 2) + 4 * kg;
                const int grow = bm0 + wr * 128 + mt * 32 + rit;
                _Float16 h = (_Float16)(float)acc[mt][nt][r] + bb;
                out[(size_t)grow * NDIM + gcol] = h;
            }
        }
    }
}

extern "C" void kernel_launch(void* const* d_in, const int* in_sizes, int n_in,
                              void* d_out, int out_size, void* d_ws, size_t ws_size,
                              hipStream_t stream) {
    const int* x = (const int*)d_in[0];
    const int* w = (const int*)d_in[1];
    const _Float16* bias = (const _Float16*)d_in[2];
    _Float16* out = (_Float16*)d_out;

    const size_t xbytes = (size_t)MDIM * KDIM;  // packed int8 bytes
    const size_t wbytes = (size_t)NDIM * KDIM;

    if (ws_size >= xbytes + wbytes) {
        char* xp = (char*)d_ws;
        char* wp = xp + xbytes;
        pack_tiled<<<1536, 256, 0, stream>>>(x, w, (uint4*)xp, (uint4*)wp);
        gemm_i8_olp<<<dim3(NDIM / BN, MDIM / BM), 512, 0, stream>>>(
            (const char*)xp, (const char*)wp, bias, out);
    } else {
        gemm_i8_fb<<<dim3(NDIM / 128, MDIM / 256), 256, 0, stream>>>(
            x, w, bias, out);
    }
}